// Round 3
// baseline (212.018 us; speedup 1.0000x reference)
//
#include <hip/hip_runtime.h>

// GRU fused, MI355X/gfx950 — round 3.
// vs r2: 512-thr blocks (8 waves), each wave owns 16 cols/gate -> weight regs
// 120->60, accs 16, total ~120 VGPR incl. AGPR-accs => 4 waves/SIMD under
// __launch_bounds__(512,4). Single barrier/step via triple-buffered lh/lx.
// Bias hoisted to registers. MB=16, grid=1024.

#define B_  16384
#define T_  28
#define F_  28
#define H_  128
#define C_  10
#define MB  16     // batch rows per block
#define LHS 136    // lh row stride in ushorts (272 B, 16B-aligned rows)
#define LXS 40     // lx row stride in ushorts (80 B)

typedef short  short8  __attribute__((ext_vector_type(8)));
typedef short  short4v __attribute__((ext_vector_type(4)));
typedef float  f32x4   __attribute__((ext_vector_type(4)));

__device__ __forceinline__ unsigned short f2bf(float f) {   // RNE fp32->bf16
    unsigned u = __builtin_bit_cast(unsigned, f);
    u += 0x7fffu + ((u >> 16) & 1u);
    return (unsigned short)(u >> 16);
}
__device__ __forceinline__ float bf2f(unsigned short h) {
    unsigned u = ((unsigned)h) << 16;
    return __builtin_bit_cast(float, u);
}
__device__ __forceinline__ float fast_sig(float x) {
    float e = __builtin_amdgcn_exp2f(x * -1.442695040888963f);
    return __builtin_amdgcn_rcpf(1.0f + e);
}
__device__ __forceinline__ float fast_tanh(float x) {
    float e = __builtin_amdgcn_exp2f(x * 2.885390081777927f);
    return 1.0f - 2.0f * __builtin_amdgcn_rcpf(1.0f + e);
}

__global__ __launch_bounds__(512, 4)
void gru_fused(const float* __restrict__ x,     // (B,T,F)
               const float* __restrict__ wk,    // (F,3H)
               const float* __restrict__ wrk,   // (H,3H)
               const float* __restrict__ bias,  // (2,3H)
               const float* __restrict__ dw,    // (H,C)
               const float* __restrict__ db,    // (C,)
               float* __restrict__ out)         // (B,C)
{
    // ---- LDS (~17.5 KB) ----
    __shared__ __align__(16) unsigned short lh[3][MB*LHS]; // h bf16, triple-buffered
    __shared__ __align__(16) unsigned short lx[3][MB*LXS]; // x_t bf16, triple-buffered
    __shared__ float llog[MB][C_];

    const int tid  = threadIdx.x;
    const int base = blockIdx.x * MB;
    const int lane = tid & 63;
    const int wc   = tid >> 6;    // wave id 0..7 -> 16-col slice per gate
    const int n    = lane & 15;   // MFMA: A row / D col
    const int q    = lane >> 4;   // MFMA quad
    const int u    = wc*16 + n;   // this lane's output column (0..127)

    // ---- loop-invariant weights -> registers (60 VGPR) ----
    // B-frag: elem(lane,j) = W[k = kb*32 + q*8 + j][u]
    short8 wz[4], wr[4], wh[4];   // W_r, gates z/r/h: 48 VGPR
    short8 xz, xr, xh;            // input kernel (K 28 padded to 32): 12 VGPR
    #pragma unroll
    for (int kb = 0; kb < 4; ++kb) {
        const int k0 = kb*32 + q*8;
        short8 vz, vr, vh;
        #pragma unroll
        for (int j = 0; j < 8; ++j) {
            const float* wp = wrk + (size_t)(k0 + j)*384 + u;
            vz[j] = (short)f2bf(wp[0]);
            vr[j] = (short)f2bf(wp[128]);
            vh[j] = (short)f2bf(wp[256]);
        }
        wz[kb] = vz; wr[kb] = vr; wh[kb] = vh;
    }
    {
        short8 vz, vr, vh;
        #pragma unroll
        for (int j = 0; j < 8; ++j) {
            const int k = q*8 + j;
            if (k < F_) {
                const float* wp = wk + (size_t)k*384 + u;
                vz[j] = (short)f2bf(wp[0]);
                vr[j] = (short)f2bf(wp[128]);
                vh[j] = (short)f2bf(wp[256]);
            } else { vz[j] = 0; vr[j] = 0; vh[j] = 0; }
        }
        xz = vz; xr = vr; xh = vh;
    }
    // ---- biases -> registers (bias_i row 0, bias_r row 384)
    const float bz = bias[u]       + bias[384 + u];
    const float brr= bias[128 + u] + bias[512 + u];
    const float bx = bias[256 + u];
    const float bh = bias[640 + u];

    // ---- h0 = 0 (buffer 0 only) ----
    for (int i = tid; i < MB*LHS/2; i += 512) ((unsigned*)lh[0])[i] = 0u;
    // ---- stage x_0 into lx[0] (cols 28..31 zeroed) ----
    if (tid < 128) {
        const int row = tid >> 3, seg = tid & 7;
        short4v v = (short4v){0,0,0,0};
        if (seg < 7) {
            float4 a = *(const float4*)(x + (size_t)(base + row)*(T_*F_) + seg*4);
            v[0]=(short)f2bf(a.x); v[1]=(short)f2bf(a.y); v[2]=(short)f2bf(a.z); v[3]=(short)f2bf(a.w);
        }
        *(short4v*)&lx[0][row*LXS + seg*4] = v;
    }

    float hm[4];                  // fp32 h master, D-layout (row q*4+reg, col u)
    #pragma unroll
    for (int r = 0; r < 4; ++r) hm[r] = 0.f;

    int br_ = 0, bn_ = 1;
    for (int t = 0; t < T_; ++t) {
        __syncthreads();   // writes of step t-1 (into br_) now visible

        // A-fragments from lh[br_]/lx[br_]: A[m=n][k=q*8+j]
        short8 ha[4], xa;
        #pragma unroll
        for (int kb = 0; kb < 4; ++kb)
            ha[kb] = *(const short8*)&lh[br_][n*LHS + kb*32 + q*8];
        xa = *(const short8*)&lx[br_][n*LXS + q*8];

        // global prefetch of x_{t+1}
        float4 pa = make_float4(0.f,0.f,0.f,0.f);
        const int prow = tid >> 3, pseg = tid & 7;
        const bool pv = (t + 1 < T_) && (tid < 128);
        if (pv && pseg < 7)
            pa = *(const float4*)(x + (size_t)(base + prow)*(T_*F_) + (t+1)*F_ + pseg*4);

        f32x4 az = (f32x4){bz,bz,bz,bz};
        f32x4 ar = (f32x4){brr,brr,brr,brr};
        f32x4 ax = (f32x4){bx,bx,bx,bx};
        f32x4 ah = (f32x4){bh,bh,bh,bh};
        #pragma unroll
        for (int kb = 0; kb < 4; ++kb) {
            az = __builtin_amdgcn_mfma_f32_16x16x32_bf16(ha[kb], wz[kb], az, 0,0,0);
            ar = __builtin_amdgcn_mfma_f32_16x16x32_bf16(ha[kb], wr[kb], ar, 0,0,0);
            ah = __builtin_amdgcn_mfma_f32_16x16x32_bf16(ha[kb], wh[kb], ah, 0,0,0);
        }
        az = __builtin_amdgcn_mfma_f32_16x16x32_bf16(xa, xz, az, 0,0,0);
        ar = __builtin_amdgcn_mfma_f32_16x16x32_bf16(xa, xr, ar, 0,0,0);
        ax = __builtin_amdgcn_mfma_f32_16x16x32_bf16(xa, xh, ax, 0,0,0);

        // gates + h update; D layout: row = q*4+reg, col = u
        #pragma unroll
        for (int reg = 0; reg < 4; ++reg) {
            float z  = fast_sig(az[reg]);
            float r  = fast_sig(ar[reg]);
            float hh = fast_tanh(ax[reg] + r * ah[reg]);
            float hn = hh + z * (hm[reg] - hh);
            hm[reg]  = hn;
            lh[bn_][(q*4 + reg)*LHS + u] = f2bf(hn);
        }
        // commit prefetched x into lx[bn_]
        if (pv || (t + 1 < T_ && tid < 128 && pseg == 7)) {
            short4v v = (short4v){0,0,0,0};
            if (pseg < 7) {
                v[0]=(short)f2bf(pa.x); v[1]=(short)f2bf(pa.y);
                v[2]=(short)f2bf(pa.z); v[3]=(short)f2bf(pa.w);
            }
            *(short4v*)&lx[bn_][prow*LXS + pseg*4] = v;
        }
        br_ = bn_; bn_ = (bn_ == 2) ? 0 : bn_ + 1;
    }

    // ---- dense + softmax epilogue (final h is in lh[br_]) ----
    __syncthreads();
    if (tid < 64) {
        const int row = tid >> 2, qq = tid & 3;
        for (int c = qq; c < C_; c += 4) {
            float s = db[c];
            #pragma unroll
            for (int u0 = 0; u0 < H_; u0 += 8) {
                short8 hv = *(const short8*)&lh[br_][row*LHS + u0];
                #pragma unroll
                for (int j = 0; j < 8; ++j)
                    s += bf2f((unsigned short)hv[j]) * dw[(u0+j)*C_ + c];
            }
            llog[row][c] = s;
        }
    }
    __syncthreads();
    if (tid < MB) {
        const int row = tid;
        float m = llog[row][0];
        #pragma unroll
        for (int c = 1; c < C_; ++c) m = fmaxf(m, llog[row][c]);
        float e[C_], s = 0.f;
        #pragma unroll
        for (int c = 0; c < C_; ++c) {
            e[c] = __builtin_amdgcn_exp2f((llog[row][c] - m) * 1.442695040888963f);
            s += e[c];
        }
        const float inv = __builtin_amdgcn_rcpf(s);
        float* o = out + (size_t)(base + row)*C_;
        #pragma unroll
        for (int c = 0; c < C_; ++c) o[c] = e[c] * inv;
    }
}

extern "C" void kernel_launch(void* const* d_in, const int* in_sizes, int n_in,
                              void* d_out, int out_size, void* d_ws, size_t ws_size,
                              hipStream_t stream) {
    const float* x   = (const float*)d_in[0];
    const float* wk  = (const float*)d_in[1];
    const float* wrk = (const float*)d_in[2];
    const float* bs  = (const float*)d_in[3];
    const float* dw  = (const float*)d_in[4];
    const float* db  = (const float*)d_in[5];
    (void)in_sizes; (void)n_in; (void)out_size; (void)d_ws; (void)ws_size;
    gru_fused<<<dim3(B_/MB), dim3(512), 0, stream>>>(x, wk, wrk, bs, dw, db, (float*)d_out);
}